// Round 4
// baseline (432.088 us; speedup 1.0000x reference)
//
#include <hip/hip_runtime.h>
#include <math.h>

// Row-normalize: out[row, :] = adj[row, :] / sum(adj[row, :]),
// with 1/0 or 1/inf -> 0 per the reference's isfinite guard.
// Shape: [2, 8, 2048, 2048] fp32 -> 32768 rows of 2048 floats.
//
// Memory-bound: 256 MiB read + 256 MiB write, each byte moved exactly once.
//
// Structure: ONE WAVE PER ROW. 64 lanes x 8 float4 = 2048 floats.
//  - row sum = in-register butterfly (__shfl_xor x6), all lanes get the sum
//  - zero __syncthreads, zero LDS -> every resident wave is an independent
//    streaming pipeline; VMEM issue never stalls on a workgroup barrier
//  - plain float4 loads/stores (nontemporal builtins dropped: two
//    consecutive container failures with them in place; their value on a
//    stream that overflows L3 anyway is ~1-2%).

#define ROW_N 2048
#define BLOCK 256
#define WAVES_PER_BLOCK (BLOCK / 64)  // 4 rows per block
#define F4_PER_LANE 8                 // 64 lanes * 8 float4 = 512 float4 = 2048 f32

__global__ __launch_bounds__(BLOCK) void normalizer_kernel(
    const float* __restrict__ adj, float* __restrict__ out, int rows) {
  const int wave = threadIdx.x >> 6;
  const int lane = threadIdx.x & 63;
  const int row = blockIdx.x * WAVES_PER_BLOCK + wave;
  if (row >= rows) return;

  const float4* __restrict__ src =
      reinterpret_cast<const float4*>(adj + (size_t)row * ROW_N);
  float4* __restrict__ dst =
      reinterpret_cast<float4*>(out + (size_t)row * ROW_N);

  // 8 coalesced float4 loads per lane (lane i -> f4[i + 64k]): 1 KiB per
  // instruction per wave, all 8 in flight before any use.
  float4 v[F4_PER_LANE];
  #pragma unroll
  for (int k = 0; k < F4_PER_LANE; ++k)
    v[k] = src[lane + 64 * k];

  float local = 0.0f;
  #pragma unroll
  for (int k = 0; k < F4_PER_LANE; ++k)
    local += (v[k].x + v[k].y) + (v[k].z + v[k].w);

  // 64-lane butterfly: every lane ends with the full row sum (no broadcast,
  // no LDS, no barrier).
  #pragma unroll
  for (int off = 32; off > 0; off >>= 1)
    local += __shfl_xor(local, off, 64);

  float inv = 1.0f / local;
  if (!isfinite(inv)) inv = 0.0f;  // matches jnp.where(isfinite(inv), inv, 0)

  #pragma unroll
  for (int k = 0; k < F4_PER_LANE; ++k) {
    float4 r = v[k];
    r.x *= inv; r.y *= inv; r.z *= inv; r.w *= inv;
    dst[lane + 64 * k] = r;
  }
}

extern "C" void kernel_launch(void* const* d_in, const int* in_sizes, int n_in,
                              void* d_out, int out_size, void* d_ws, size_t ws_size,
                              hipStream_t stream) {
  const float* adj = (const float*)d_in[0];
  float* out = (float*)d_out;
  const int rows = out_size / ROW_N;  // 2*8*2048 = 32768
  const int grid = (rows + WAVES_PER_BLOCK - 1) / WAVES_PER_BLOCK;
  normalizer_kernel<<<grid, BLOCK, 0, stream>>>(adj, out, rows);
}

// Round 5
// 420.146 us; speedup vs baseline: 1.0284x; 1.0284x over previous
//
#include <hip/hip_runtime.h>
#include <math.h>

// Row-normalize: out[row, :] = adj[row, :] / sum(adj[row, :]),
// with 1/0 or 1/inf -> 0 per the reference's isfinite guard.
// Shape: [2, 8, 2048, 2048] fp32 -> 32768 rows of 2048 floats.
//
// Memory-bound: 256 MiB read + 256 MiB write, each byte moved exactly once.
// Measured copy ceiling 6.29 TB/s -> 85.4 us floor; kernel is ~95-100 us.
//
// Structure (A/B vs round 4: ONLY change is nontemporal load/store):
//  - ONE WAVE PER ROW: 64 lanes x 8 float4 = 2048 floats
//  - row sum = in-register butterfly (__shfl_xor x6), zero LDS, zero barriers
//  - nontemporal on both streams: every byte is touched exactly once and the
//    512 MiB working set overflows the 256 MiB L3, so cache retention is
//    pure churn; `nt` skips it.
//
// NOTE: __builtin_nontemporal_* requires a NATIVE vector type (ext_vector),
// not HIP's float4 struct — hence f32x4 (same 16-B layout/alignment).

#define ROW_N 2048
#define BLOCK 256
#define WAVES_PER_BLOCK (BLOCK / 64)  // 4 rows per block
#define F4_PER_LANE 8                 // 64 lanes * 8 float4 = 512 float4 = 2048 f32

typedef float f32x4 __attribute__((ext_vector_type(4)));

__global__ __launch_bounds__(BLOCK) void normalizer_kernel(
    const float* __restrict__ adj, float* __restrict__ out, int rows) {
  const int wave = threadIdx.x >> 6;
  const int lane = threadIdx.x & 63;
  const int row = blockIdx.x * WAVES_PER_BLOCK + wave;
  if (row >= rows) return;

  const f32x4* __restrict__ src =
      reinterpret_cast<const f32x4*>(adj + (size_t)row * ROW_N);
  f32x4* __restrict__ dst =
      reinterpret_cast<f32x4*>(out + (size_t)row * ROW_N);

  // 8 coalesced 16-B loads per lane (lane i -> f4[i + 64k]): 1 KiB per
  // instruction per wave, all 8 in flight before any use.
  f32x4 v[F4_PER_LANE];
  #pragma unroll
  for (int k = 0; k < F4_PER_LANE; ++k)
    v[k] = __builtin_nontemporal_load(&src[lane + 64 * k]);

  float local = 0.0f;
  #pragma unroll
  for (int k = 0; k < F4_PER_LANE; ++k)
    local += (v[k].x + v[k].y) + (v[k].z + v[k].w);

  // 64-lane butterfly: every lane ends with the full row sum (no broadcast,
  // no LDS, no barrier).
  #pragma unroll
  for (int off = 32; off > 0; off >>= 1)
    local += __shfl_xor(local, off, 64);

  float inv = 1.0f / local;
  if (!isfinite(inv)) inv = 0.0f;  // matches jnp.where(isfinite(inv), inv, 0)

  #pragma unroll
  for (int k = 0; k < F4_PER_LANE; ++k) {
    f32x4 r = v[k];
    r.x *= inv; r.y *= inv; r.z *= inv; r.w *= inv;
    __builtin_nontemporal_store(r, &dst[lane + 64 * k]);
  }
}

extern "C" void kernel_launch(void* const* d_in, const int* in_sizes, int n_in,
                              void* d_out, int out_size, void* d_ws, size_t ws_size,
                              hipStream_t stream) {
  const float* adj = (const float*)d_in[0];
  float* out = (float*)d_out;
  const int rows = out_size / ROW_N;  // 2*8*2048 = 32768
  const int grid = (rows + WAVES_PER_BLOCK - 1) / WAVES_PER_BLOCK;
  normalizer_kernel<<<grid, BLOCK, 0, stream>>>(adj, out, rows);
}